// Round 5
// baseline (345.513 us; speedup 1.0000x reference)
//
#include <hip/hip_runtime.h>
#include <hip/hip_bf16.h>
#include <stdint.h>

#define B_ 8
#define C_ 1024
#define D_ 128
#define L_ 2048

typedef __attribute__((ext_vector_type(8))) short short8;
typedef __attribute__((ext_vector_type(4))) float floatx4;

// async global->LDS direct copy, 16 bytes per lane
#define GLDS16(g, l)                                                          \
    __builtin_amdgcn_global_load_lds(                                         \
        (const __attribute__((address_space(1))) uint32_t*)(g),               \
        (__attribute__((address_space(3))) uint32_t*)(l), 16, 0, 0)

__device__ inline float b2f(uint16_t u) {
    union { uint32_t i; float f; } x; x.i = (uint32_t)u << 16; return x.f;
}
__device__ inline uint16_t f2b(float f) {
    union { uint32_t i; float f; } x; x.f = f;
    uint32_t r = (x.i + 0x7fff + ((x.i >> 16) & 1)) >> 16;
    return (uint16_t)r;
}

// ---------------- small cast kernel: f32 -> bf16 ----------------
__global__ void cast_f32_bf16(const float* __restrict__ src, uint16_t* __restrict__ dst, int n) {
    int i = blockIdx.x * 256 + threadIdx.x;
    if (i < n) dst[i] = f2b(src[i]);
}

// ---------------- transpose + cast: x [B][C][L] f32 -> xT [B][L][C] bf16 ----------------
__global__ __launch_bounds__(256) void transpose_cast(const float* __restrict__ x, uint16_t* __restrict__ xT) {
    __shared__ float tile[32][33];
    int b = blockIdx.z;
    int l0 = blockIdx.x * 32, c0 = blockIdx.y * 32;
    int tx = threadIdx.x, ty = threadIdx.y;  // blockDim (32, 8)
    const float* xb = x + (size_t)b * C_ * L_;
#pragma unroll
    for (int i = 0; i < 4; i++)
        tile[ty + i * 8][tx] = xb[(size_t)(c0 + ty + i * 8) * L_ + l0 + tx];
    __syncthreads();
    uint16_t* xtb = xT + (size_t)b * L_ * C_;
#pragma unroll
    for (int i = 0; i < 4; i++) {
        int l = l0 + ty + i * 8, c = c0 + tx;
        xtb[(size_t)l * C_ + c] = f2b(tile[tx][ty + i * 8]);
    }
}

// ---------------- qk GEMM (128^2 tile, validated r2 structure) ----------------
__global__ __launch_bounds__(256) void gemm_qk(
    const uint16_t* __restrict__ A, const uint16_t* __restrict__ B, long sB,
    const float* __restrict__ bq, const float* __restrict__ bk,
    uint16_t* __restrict__ Cout, long sC, int K) {

    __shared__ uint4 As4[512];  // 128 x 32 bf16
    __shared__ uint4 Bs4[512];
    uint16_t* As = (uint16_t*)As4;
    uint16_t* Bs = (uint16_t*)Bs4;

    const int b = blockIdx.z;
    const uint16_t* Ab = A;
    const uint16_t* Bb = B + (size_t)b * sB;
    const int m0 = blockIdx.y * 128;
    const int n0 = blockIdx.x * 128;

    const int t = threadIdx.x;
    const int lane = t & 63;
    const int wave = t >> 6;
    const int wm = (wave >> 1) * 64;
    const int wn = (wave & 1) * 64;

    floatx4 acc[4][4] = {};

    const int c0 = t, c1 = t + 256;
    const uint16_t* gA0 = Ab + (size_t)(m0 + (c0 >> 2)) * K + (c0 & 3) * 8;
    const uint16_t* gA1 = Ab + (size_t)(m0 + (c1 >> 2)) * K + (c1 & 3) * 8;
    const uint16_t* gB0 = Bb + (size_t)(n0 + (c0 >> 2)) * K + (c0 & 3) * 8;
    const uint16_t* gB1 = Bb + (size_t)(n0 + (c1 >> 2)) * K + (c1 & 3) * 8;

    for (int k0 = 0; k0 < K; k0 += 32) {
        __syncthreads();
        GLDS16(gA0 + k0, &As4[c0]);
        GLDS16(gA1 + k0, &As4[c1]);
        GLDS16(gB0 + k0, &Bs4[c0]);
        GLDS16(gB1 + k0, &Bs4[c1]);
        __syncthreads();

        const int kg = (lane >> 4) * 8;
        const int rA = wm + (lane & 15);
        const int rB = wn + (lane & 15);
        short8 af[4], bf[4];
#pragma unroll
        for (int i = 0; i < 4; i++) af[i] = *(const short8*)(As + (rA + i * 16) * 32 + kg);
#pragma unroll
        for (int j = 0; j < 4; j++) bf[j] = *(const short8*)(Bs + (rB + j * 16) * 32 + kg);
#pragma unroll
        for (int i = 0; i < 4; i++)
#pragma unroll
            for (int j = 0; j < 4; j++)
                acc[i][j] = __builtin_amdgcn_mfma_f32_16x16x32_bf16(af[i], bf[j], acc[i][j], 0, 0, 0);
    }

    uint16_t* Cb = Cout + (size_t)b * sC;
#pragma unroll
    for (int i = 0; i < 4; i++)
#pragma unroll
        for (int j = 0; j < 4; j++) {
            int mrow = m0 + wm + i * 16 + ((lane >> 4) << 2);
            int ncol = n0 + wn + j * 16 + (lane & 15);
#pragma unroll
            for (int r = 0; r < 4; r++) {
                int mr = mrow + r;
                float val = acc[i][j][r] + (mr < 128 ? bq[mr] : bk[mr - 128]);
                Cb[(size_t)ncol * 256 + mr] = f2b(val);  // transposed store into [L][256]
            }
        }
}

// ============ 128^2 tile, BK=32, 4 waves, ring-4 counted-vmcnt, 2 blocks/CU ============
// C[m][n] = sum_k A[m][k]*B[n][k], bf16 in, f32 acc.
// Per K-tile kt (slot kt&3):
//   8 ds_read (af0..3, bf0..3) | issue 4 global_load_lds for tile kt+3 -> slot (kt-1)&3
//   lgkmcnt(0); setprio(1); 16 MFMA; setprio(0); vmcnt(4*ahead); s_barrier
// Ring ordering proof: GLDS(kt+3) targets slot (kt+3)&3=(kt-1)&3, whose last reads
// were in tile kt-1, separated from this issue by the kt-1 boundary barrier.
// T2 swizzle (validated r4): LDS slot (r,c) holds global chunk c ^ ((r^(r>>2))&3);
// both +16-row and +64-row offsets preserve the swizzle term.
template <int EPI>
__global__ __launch_bounds__(256, 2) void gemm128(
    const uint16_t* __restrict__ A, const uint16_t* __restrict__ B,
    int lda, int ldb, long sA, long sB, const float* __restrict__ bias,
    void* __restrict__ Cout, long sC, int ldc, int K,
    const float* __restrict__ gamma, const float* __restrict__ X) {

    __shared__ uint4 AS[4][512];  // 4 ring slots x (128 rows x 64B) = 8KB each
    __shared__ uint4 BS[4][512];  // total LDS 64KB -> 2 blocks/CU

    const int b = blockIdx.z;
    const uint16_t* Ab = A + (size_t)b * sA;
    const uint16_t* Bb = B + (size_t)b * sB;
    const int m0 = blockIdx.y * 128;
    const int n0 = blockIdx.x * 128;

    const int t = threadIdx.x;          // 256 threads = 4 waves
    const int lane = t & 63;
    const int wid = t >> 6;
    const int wm = (wid >> 1) * 64;     // 2 M-waves
    const int wn = (wid & 1) * 64;      // 2 N-waves

    // ---- stage constants: thread t owns 16B LDS slots t (rows 0-63) and t+256 (rows 64-127)
    const int srow = t >> 2;                                // 0..63
    const int sc = ((t & 3) ^ (srow ^ (srow >> 2))) & 3;    // inverse-swizzled source chunk
    const uint16_t* gA0 = Ab + (size_t)(m0 + srow) * lda + sc * 8;
    const uint16_t* gA1 = gA0 + (size_t)64 * lda;
    const uint16_t* gB0 = Bb + (size_t)(n0 + srow) * ldb + sc * 8;
    const uint16_t* gB1 = gB0 + (size_t)64 * ldb;

    // ---- ds_read constants (halfword offsets)
    const int rsw = ((lane >> 4) ^ (lane ^ (lane >> 2))) & 3;   // swizzled chunk
    const int aoff = (wm + (lane & 15)) * 32 + rsw * 8;
    const int boff = (wn + (lane & 15)) * 32 + rsw * 8;

    floatx4 acc[4][4] = {};
    const int nt = K >> 5;

#define STAGE(slot, k0) do {                         \
        GLDS16(gA0 + (k0), &AS[slot][t]);            \
        GLDS16(gA1 + (k0), &AS[slot][t + 256]);      \
        GLDS16(gB0 + (k0), &BS[slot][t]);            \
        GLDS16(gB1 + (k0), &BS[slot][t + 256]);      \
    } while (0)

    // ---- prologue: stage tiles 0,1,2; wait tile 0 landed (leave 1,2 in flight)
    STAGE(0, 0);
    if (nt > 1) STAGE(1, 32);
    if (nt > 2) STAGE(2, 64);
    if (nt > 2)      asm volatile("s_waitcnt vmcnt(8)" ::: "memory");
    else if (nt > 1) asm volatile("s_waitcnt vmcnt(4)" ::: "memory");
    else             asm volatile("s_waitcnt vmcnt(0)" ::: "memory");
    __builtin_amdgcn_s_barrier();
    __builtin_amdgcn_sched_barrier(0);

    for (int kt = 0; kt < nt; kt++) {
        const int slot = kt & 3;
        const uint16_t* Ap = (const uint16_t*)AS[slot];
        const uint16_t* Bp = (const uint16_t*)BS[slot];

        short8 af[4], bf[4];
#pragma unroll
        for (int i = 0; i < 4; i++) af[i] = *(const short8*)(Ap + aoff + i * 512);
#pragma unroll
        for (int j = 0; j < 4; j++) bf[j] = *(const short8*)(Bp + boff + j * 512);
        if (kt + 3 < nt) STAGE((kt + 3) & 3, (kt + 3) * 32);

        asm volatile("s_waitcnt lgkmcnt(0)" ::: "memory");
        __builtin_amdgcn_sched_barrier(0);
        __builtin_amdgcn_s_setprio(1);
#pragma unroll
        for (int i = 0; i < 4; i++)
#pragma unroll
            for (int j = 0; j < 4; j++)
                acc[i][j] = __builtin_amdgcn_mfma_f32_16x16x32_bf16(af[i], bf[j], acc[i][j], 0, 0, 0);
        __builtin_amdgcn_s_setprio(0);

        // ---- K-tile boundary: counted drain guarantees kt+1 landed block-wide
        if (kt + 1 < nt) {
            const int inflight_last = (nt - 1 < kt + 3) ? (nt - 1) : (kt + 3);
            const int ahead = inflight_last - (kt + 1);   // 0..2 tiles beyond kt+1
            if (ahead >= 2)      asm volatile("s_waitcnt vmcnt(8)" ::: "memory");
            else if (ahead == 1) asm volatile("s_waitcnt vmcnt(4)" ::: "memory");
            else                 asm volatile("s_waitcnt vmcnt(0)" ::: "memory");
            __builtin_amdgcn_s_barrier();
            __builtin_amdgcn_sched_barrier(0);
        }
    }
#undef STAGE

    if (EPI == 0 || EPI == 2) {
        uint16_t* Cb = (uint16_t*)Cout + (size_t)b * sC;
#pragma unroll
        for (int mi = 0; mi < 4; mi++)
#pragma unroll
            for (int nj = 0; nj < 4; nj++) {
                int mrow = m0 + wm + mi * 16 + ((lane >> 4) << 2);
                int ncol = n0 + wn + nj * 16 + (lane & 15);
#pragma unroll
                for (int r = 0; r < 4; r++) {
                    float val = acc[mi][nj][r];
                    if (EPI == 0) val += bias[mrow + r];
                    Cb[(size_t)(mrow + r) * ldc + ncol] = f2b(val);
                }
            }
    } else {  // EPI == 3
        float g = gamma[0];
        float* Ob = (float*)Cout + (size_t)b * sC;
        const float* Xb = X + (size_t)b * sC;
#pragma unroll
        for (int mi = 0; mi < 4; mi++)
#pragma unroll
            for (int nj = 0; nj < 4; nj++) {
                int mrow = m0 + wm + mi * 16 + ((lane >> 4) << 2);
                int ncol = n0 + wn + nj * 16 + (lane & 15);
#pragma unroll
                for (int r = 0; r < 4; r++) {
                    size_t idx = (size_t)(mrow + r) * ldc + ncol;
                    Ob[idx] = g * acc[mi][nj][r] + Xb[idx];
                }
            }
    }
}

// ---------------- row softmax, in-place bf16, one block per row ----------------
__global__ __launch_bounds__(256) void softmax_rows(uint16_t* __restrict__ att) {
    const int i = blockIdx.x, b = blockIdx.y;
    uint16_t* row = att + ((size_t)b * L_ + i) * L_;
    const int t = threadIdx.x;
    short8 v = *(const short8*)(row + t * 8);
    float f[8];
    float m = -1e30f;
#pragma unroll
    for (int e = 0; e < 8; e++) { f[e] = b2f((uint16_t)v[e]); m = fmaxf(m, f[e]); }
#pragma unroll
    for (int off = 32; off >= 1; off >>= 1) m = fmaxf(m, __shfl_xor(m, off));
    __shared__ float redm[4], reds[4];
    const int wave = t >> 6;
    if ((t & 63) == 0) redm[wave] = m;
    __syncthreads();
    m = fmaxf(fmaxf(redm[0], redm[1]), fmaxf(redm[2], redm[3]));
    float s = 0.f;
#pragma unroll
    for (int e = 0; e < 8; e++) { f[e] = __expf(f[e] - m); s += f[e]; }
#pragma unroll
    for (int off = 32; off >= 1; off >>= 1) s += __shfl_xor(s, off);
    if ((t & 63) == 0) reds[wave] = s;
    __syncthreads();
    s = reds[0] + reds[1] + reds[2] + reds[3];
    float inv = 1.0f / s;
    short8 o;
#pragma unroll
    for (int e = 0; e < 8; e++) o[e] = (short)f2b(f[e] * inv);
    *(short8*)(row + t * 8) = o;
}

// ---------------- workspace layout (bytes), total 145,227,776 ----------------
#define OFF_XT   0ull           // 33,554,432  xT  [B][L][C] bf16
#define OFF_QK   33554432ull    //  8,388,608  qk  [B][L][256] bf16
#define OFF_V    41943040ull    // 33,554,432  v   [B][C][L] bf16
#define OFF_ATT  75497472ull    // 67,108,864  att [B][L][L] bf16
#define OFF_WQK  142606336ull   //    524,288  Wqk [256][1024] bf16
#define OFF_WV   143130624ull   //  2,097,152  Wv  [1024][1024] bf16

extern "C" void kernel_launch(void* const* d_in, const int* in_sizes, int n_in,
                              void* d_out, int out_size, void* d_ws, size_t ws_size,
                              hipStream_t stream) {
    const float* x  = (const float*)d_in[0];
    const float* Wq = (const float*)d_in[1];
    const float* bq = (const float*)d_in[2];
    const float* Wk = (const float*)d_in[3];
    const float* bk = (const float*)d_in[4];
    const float* Wv = (const float*)d_in[5];
    const float* bv = (const float*)d_in[6];
    const float* gamma = (const float*)d_in[7];
    float* out = (float*)d_out;
    char* ws = (char*)d_ws;

    uint16_t* xT   = (uint16_t*)(ws + OFF_XT);
    uint16_t* qk   = (uint16_t*)(ws + OFF_QK);
    uint16_t* v    = (uint16_t*)(ws + OFF_V);
    uint16_t* att  = (uint16_t*)(ws + OFF_ATT);
    uint16_t* Wqkb = (uint16_t*)(ws + OFF_WQK);
    uint16_t* Wvb  = (uint16_t*)(ws + OFF_WV);

    // 1. weight casts (Wq into rows 0-127, Wk into rows 128-255 of Wqk)
    cast_f32_bf16<<<dim3((D_ * C_ + 255) / 256), 256, 0, stream>>>(Wq, Wqkb, D_ * C_);
    cast_f32_bf16<<<dim3((D_ * C_ + 255) / 256), 256, 0, stream>>>(Wk, Wqkb + D_ * C_, D_ * C_);
    cast_f32_bf16<<<dim3((C_ * C_ + 255) / 256), 256, 0, stream>>>(Wv, Wvb, C_ * C_);

    // 2. x transpose+cast: [B][C][L] f32 -> [B][L][C] bf16
    transpose_cast<<<dim3(L_ / 32, C_ / 32, B_), dim3(32, 8), 0, stream>>>(x, xT);

    // 3. q,k in one dispatch: qk[b][l][0:128]=q, [128:256]=k (transposed store)
    gemm_qk<<<dim3(L_ / 128, 2, B_), 256, 0, stream>>>(
        Wqkb, xT, (long)L_ * C_, bq, bk, qk, (long)L_ * 256, C_);

    // 4. v = Wv*x (+bv), stored [B][C][L]
    gemm128<0><<<dim3(L_ / 128, C_ / 128, B_), 256, 0, stream>>>(
        Wvb, xT, C_, C_, 0, (long)L_ * C_, bv, v, (long)C_ * L_, L_, C_, nullptr, nullptr);

    // 5. energy[b][i][j] = sum_d q[b][i][d]*k[b][j][d] -> bf16 att
    gemm128<2><<<dim3(L_ / 128, L_ / 128, B_), 256, 0, stream>>>(
        qk, qk + 128, 256, 256, (long)L_ * 256, (long)L_ * 256, nullptr,
        att, (long)L_ * L_, L_, D_, nullptr, nullptr);

    // 6. softmax rows, in place
    softmax_rows<<<dim3(L_, B_), 256, 0, stream>>>(att);

    // 7. out[b][c][i] = gamma * sum_j v[b][c][j]*att[b][i][j] + x[b][c][i]
    gemm128<3><<<dim3(L_ / 128, C_ / 128, B_), 256, 0, stream>>>(
        v, att, L_, L_, (long)C_ * L_, (long)L_ * L_, nullptr,
        out, (long)C_ * L_, L_, L_, gamma, x);
}